// Round 6
// baseline (325.287 us; speedup 1.0000x reference)
//
#include <hip/hip_runtime.h>
#include <cstdint>
#include <cstddef>

typedef _Float16 f16;
typedef f16 f16x2 __attribute__((ext_vector_type(2)));
typedef f16 f16x4 __attribute__((ext_vector_type(4)));
typedef f16 f16x8 __attribute__((ext_vector_type(8)));
typedef float f32x4 __attribute__((ext_vector_type(4)));

#define NEXP 8
#define BM 128
#define BN 128
#define BK 32
#define NSTAGE 2
#define TPW 4

// async global->LDS, 16B per lane. LDS dest must be wave-uniform base + lane*16
// (staging index is tid*16 so this holds). Global source may be per-lane
// arbitrary (gathered rows / swizzled chunks are fine).
__device__ __forceinline__ void async_cp16(void* lds, const void* gsrc) {
  __builtin_amdgcn_global_load_lds(
      (const __attribute__((address_space(1))) void*)gsrc,
      (__attribute__((address_space(3))) void*)lds, 16, 0, 0);
}

// ---------------- fusedA: gate-role + wfull-role in one dispatch -------------
// Blocks [0, ngate): gating (LDS-staged gw, 4 tokens/wave, ideal traffic).
// Blocks [ngate, ...): Wfull^T construction.
// The two roles are data-independent -> they overlap on the machine instead
// of serializing as two memory-bound kernels + a launch gap.
// Shared memory is a 33 KB union: gate uses gws[8][1028]f32 + ps/pc;
// wfull uses Wt[4][32][33]f32 (16.9 KB).
__global__ __launch_bounds__(256) void k_fusedA(
    const float* __restrict__ x, const float* __restrict__ gw,
    f16* __restrict__ xb, int* __restrict__ gate, float* __restrict__ scale,
    int* __restrict__ cnt, float* __restrict__ probsum,
    const float* __restrict__ Wp, const float* __restrict__ rule,
    f16* __restrict__ wt,
    int D, int Dp, int Op, int O, int ngate)
{
  __shared__ __align__(16) uint8_t smem[NEXP * 1028 * 4 + 64];
  int tid = threadIdx.x;

  if ((int)blockIdx.x < ngate) {
    // ================= gate role =================
    float (*gws)[1028] = (float(*)[1028])smem;            // [8][1028]
    float* ps = (float*)(smem + NEXP * 1028 * 4);         // [8]
    int*   pc = (int*)(smem + NEXP * 1028 * 4 + 32);      // [8]
    int lane = tid & 63, w = tid >> 6;
    if (tid < NEXP) { ps[tid] = 0.f; pc[tid] = 0; }

    int t0 = (blockIdx.x * 4 + w) * TPW;     // wave's first token
    const float* xr = x + (size_t)t0 * D;
    f16* xbr = xb + (size_t)t0 * D;

    float acc[TPW][NEXP] = {};
    int nh = D >> 10;                        // half-passes of 1024 d each
    for (int half = 0; half < nh; half++) {
      __syncthreads();   // prev pass reads (and ps/pc init) done before restage
      const float2* gsrc = (const float2*)(gw + (size_t)half * 1024 * NEXP);
      for (int i = tid; i < 4096; i += 256) {
        float2 v = gsrc[i];
        int f = i * 2;
        int d = f >> 3, e = f & 7;
        gws[e][d] = v.x;
        gws[e + 1][d] = v.y;
      }
      __syncthreads();

      int dh = half << 10;
#pragma unroll
      for (int it = 0; it < 4; it++) {
        int d0 = lane * 4 + it * 256;        // local d within this half
        float4 xv[TPW];
#pragma unroll
        for (int tp = 0; tp < TPW; tp++) {
          xv[tp] = *(const float4*)(xr + (size_t)tp * D + dh + d0);
          f16x4 h;
          h[0] = (f16)xv[tp].x; h[1] = (f16)xv[tp].y;
          h[2] = (f16)xv[tp].z; h[3] = (f16)xv[tp].w;
          *(f16x4*)(xbr + (size_t)tp * D + dh + d0) = h;
        }
#pragma unroll
        for (int e = 0; e < NEXP; e++) {
          float4 g = *(const float4*)&gws[e][d0];   // conflict-free, reused x4
#pragma unroll
          for (int tp = 0; tp < TPW; tp++)
            acc[tp][e] += xv[tp].x * g.x + xv[tp].y * g.y +
                          xv[tp].z * g.z + xv[tp].w * g.w;
        }
      }
    }

#pragma unroll
    for (int tp = 0; tp < TPW; tp++)
#pragma unroll
      for (int e = 0; e < NEXP; e++) {
        float v = acc[tp][e];
        for (int o = 32; o > 0; o >>= 1) v += __shfl_xor(v, o);
        acc[tp][e] = v;
      }

    if (lane == 0) {
#pragma unroll
      for (int tp = 0; tp < TPW; tp++) {
        float m = acc[tp][0]; int g = 0;
#pragma unroll
        for (int e = 1; e < NEXP; e++)
          if (acc[tp][e] > m) { m = acc[tp][e]; g = e; }
        float pr[NEXP]; float ssum = 0.f;
#pragma unroll
        for (int e = 0; e < NEXP; e++) { pr[e] = __expf(acc[tp][e] - m); ssum += pr[e]; }
        float inv = 1.0f / ssum;
#pragma unroll
        for (int e = 0; e < NEXP; e++) atomicAdd(&ps[e], pr[e] * inv);
        atomicAdd(&pc[g], 1);
        gate[t0 + tp] = g;
        scale[t0 + tp] = pr[g] * inv;
      }
    }
    __syncthreads();
    if (tid < NEXP) {
      atomicAdd(&probsum[tid], ps[tid]);
      atomicAdd(&cnt[tid], pc[tid]);
    }
  } else {
    // ================= wfull role =================
    // wt[e][n][d] = sum_p rule[e,p,a,b] * W[e,p,i,j], d = a*Dp+i, n = b*Op+j.
    float (*Wt)[32][33] = (float(*)[32][33])smem;         // [4][32][33]
    int bid = blockIdx.x - ngate;
    int it = Dp >> 5, jt = Op >> 5;
    int itile = bid % it; bid /= it;
    int jtile = bid % jt; bid /= jt;
    int e = bid;
    int i0 = itile * 32, j0 = jtile * 32;

    for (int idx = tid; idx < 4096; idx += 256) {
      int p = idx >> 10, rem = idx & 1023, ii = rem >> 5, jj = rem & 31;
      Wt[p][ii][jj] = Wp[(size_t)((e * 4 + p) * Dp + i0 + ii) * Op + j0 + jj];
    }
    __syncthreads();

    int r = tid >> 1;        // 0..127 output rows of this block
    int b = r >> 5;          // wave-uniform
    int jj = r & 31;
    int h = tid & 1;         // d-half: i = h*16 + k

    float s[4][4];
#pragma unroll
    for (int p = 0; p < 4; p++)
#pragma unroll
      for (int a = 0; a < 4; a++)
        s[p][a] = rule[((e * 4 + p) * 4 + a) * 4 + b];

    f16x8 outv[4][2];
#pragma unroll
    for (int k = 0; k < 16; k++) {
      int i = h * 16 + k;
      float w0 = Wt[0][i][jj], w1 = Wt[1][i][jj];
      float w2 = Wt[2][i][jj], w3 = Wt[3][i][jj];
#pragma unroll
      for (int a = 0; a < 4; a++) {
        float acc = s[0][a] * w0 + s[1][a] * w1 + s[2][a] * w2 + s[3][a] * w3;
        outv[a][k >> 3][k & 7] = (f16)acc;
      }
    }

    size_t rowbase = ((size_t)e * O + (size_t)b * Op + j0 + jj) * D + i0 + h * 16;
#pragma unroll
    for (int a = 0; a < 4; a++) {
      *(f16x8*)(wt + rowbase + (size_t)a * Dp)     = outv[a][0];
      *(f16x8*)(wt + rowbase + (size_t)a * Dp + 8) = outv[a][1];
    }
  }
}

// ---------------- fusedB: plan (block 0) + scatter (blocks 1..T/256) ---------
// scatter no longer depends on plan's offs: each scatter block recomputes the
// 8-element exclusive scan of cnt in registers. plan still writes global offs
// for k_gemm. cursor zeroed by the launch-side memset.
__global__ __launch_bounds__(256) void k_fusedB(
    const int* __restrict__ cnt, const float* __restrict__ probsum,
    const int* __restrict__ gate, int* __restrict__ offs,
    int* __restrict__ ndesc, int2* __restrict__ desc,
    int* __restrict__ cursor, int* __restrict__ perm,
    float* __restrict__ otail, int T)
{
  int tid = threadIdx.x;
  if (blockIdx.x == 0) {
    // ---- plan ----
    __shared__ int soffs[NEXP + 1];
    __shared__ int snd;
    __shared__ float sloss;
    __shared__ int2 sdesc[96];
    if (tid == 0) {
      int off = 0, nd = 0; float loss = 0.f;
      for (int e = 0; e < NEXP; e++) {
        soffs[e] = off;
        int c = cnt[e];
        loss += probsum[e] * (float)c;
        for (int m0 = 0; m0 < c; m0 += BM) { sdesc[nd] = make_int2(e, m0); nd++; }
        off += c;
      }
      soffs[NEXP] = off;
      snd = nd;
      sloss = loss;
    }
    __syncthreads();
    if (tid <= NEXP) offs[tid] = soffs[tid];
    if (tid == 9) *ndesc = snd;
    if (tid == 10) {
      float invT = 1.0f / (float)T;
      otail[0] = (float)NEXP * sloss * invT * invT;  // balance loss
    }
    if (tid >= 16 && tid < 16 + NEXP) otail[1 + tid - 16] = (float)cnt[tid - 16];
    for (int i = tid; i < snd; i += 256) desc[i] = sdesc[i];
  } else {
    // ---- scatter ----
    int t = (blockIdx.x - 1) * 256 + tid;
    int g = gate[t];
    int lane = tid & 63;
    // local exclusive scan of cnt (8 ints, L2-broadcast)
    int lofs[NEXP];
    {
      int run = 0;
#pragma unroll
      for (int e = 0; e < NEXP; e++) { lofs[e] = run; run += cnt[e]; }
    }
    int pos = 0;
#pragma unroll
    for (int e = 0; e < NEXP; e++) {
      unsigned long long mask = __ballot(g == e);
      if (mask == 0ull) continue;            // wave-uniform
      int leader = __ffsll((unsigned long long)mask) - 1;
      int base = 0;
      if (lane == leader) base = atomicAdd(&cursor[e], (int)__popcll(mask));
      base = __shfl(base, leader);
      if (g == e) {
        int below = (int)__popcll(mask & ((1ull << lane) - 1ull));
        pos = lofs[e] + base + below;
      }
    }
    perm[pos] = t;
  }
}

// ---------------- K5: gathered top-1 GEMM ----------------
// 128x128 tile, BK=32, 2-stage LDS pipeline (prefetch distance 1), counted
// vmcnt, XOR bank swizzle. Frozen: 122-126 us across NSTAGE={2,3}, 3 vs 4
// blocks/CU, and two 256x256 8-phase rewrites (both regressed). MfmaUtil ~24%.
__global__ __launch_bounds__(256) void k_gemm(
    const f16* __restrict__ xb, const f16* __restrict__ wt,
    const float* __restrict__ bias, const int* __restrict__ perm,
    const int* __restrict__ cnt, const int* __restrict__ offs,
    const int* __restrict__ ndesc, const int2* __restrict__ desc,
    const float* __restrict__ scale, float* __restrict__ out, int D, int O)
{
  if ((int)blockIdx.y >= *ndesc) return;
  int2 dsc = desc[blockIdx.y];
  int e = dsc.x, m0 = dsc.y;
  int ce = cnt[e];
  int seg = offs[e];
  int n0 = blockIdx.x * BN;

  __shared__ f16 Al[NSTAGE][BM * BK];   // 2 x 8KB
  __shared__ f16 Bl[NSTAGE][BN * BK];   // 2 x 8KB
  __shared__ int tokS[BM];
  __shared__ float scS[BM];

  int tid = threadIdx.x;
  if (tid < BM) {
    int idx = m0 + tid; if (idx > ce - 1) idx = ce - 1;  // clamp partial tile
    int tok = perm[seg + idx];
    tokS[tid] = tok;
    scS[tid] = scale[tok];
  }
  __syncthreads();

  // staging: thread owns 16B chunk c of rows r and r+64; fetches global chunk
  // gc = c ^ ((r>>1)&3); MFMA reader un-swizzles with the same xor.
  int r = tid >> 2;   // 0..63
  int c = tid & 3;
  int gc = c ^ ((r >> 1) & 3);
  const f16* a1 = xb + (size_t)tokS[r] * D + gc * 8;
  const f16* a2 = xb + (size_t)tokS[r + 64] * D + gc * 8;
  const f16* b1 = wt + ((size_t)e * O + n0 + r) * D + gc * 8;
  const f16* b2 = wt + ((size_t)e * O + n0 + r + 64) * D + gc * 8;

  int lane = tid & 63;
  int w = tid >> 6;
  int wm = (w & 1) * 64, wn = (w >> 1) * 64;
  int lr = lane & 15, q = lane >> 4;
  int qs = q ^ ((lr >> 1) & 3);  // swizzled read chunk

  f32x4 acc[4][4] = {};
  int nk = D / BK;

#define STAGE(kk, p)                                             \
  do {                                                           \
    async_cp16(&Al[(p)][tid * 8], a1 + (kk) * BK);               \
    async_cp16(&Al[(p)][2048 + tid * 8], a2 + (kk) * BK);        \
    async_cp16(&Bl[(p)][tid * 8], b1 + (kk) * BK);               \
    async_cp16(&Bl[(p)][2048 + tid * 8], b2 + (kk) * BK);        \
  } while (0)

  STAGE(0, 0);
  STAGE(1, 1);

  int p = 0;
  for (int kk = 0; kk < nk; ++kk) {
    // tile kk must be complete; tile kk+1 (4 loads) may stay in flight
    if (kk + 1 < nk)
      asm volatile("s_waitcnt vmcnt(4)\n\ts_barrier" ::: "memory");
    else
      asm volatile("s_waitcnt vmcnt(0)\n\ts_barrier" ::: "memory");

    f16x8 af[4], bf[4];
#pragma unroll
    for (int mi = 0; mi < 4; mi++)
      af[mi] = *(const f16x8*)&Al[p][(wm + mi * 16 + lr) * BK + qs * 8];
#pragma unroll
    for (int ni = 0; ni < 4; ni++)
      bf[ni] = *(const f16x8*)&Bl[p][(wn + ni * 16 + lr) * BK + qs * 8];

    // all waves' ds_reads of buffer p done -> safe to restage it
    asm volatile("s_waitcnt lgkmcnt(0)\n\ts_barrier" ::: "memory");
    if (kk + NSTAGE < nk) STAGE(kk + NSTAGE, p);

#pragma unroll
    for (int mi = 0; mi < 4; mi++)
#pragma unroll
      for (int ni = 0; ni < 4; ni++)
        acc[mi][ni] = __builtin_amdgcn_mfma_f32_16x16x32_f16(
            af[mi], bf[ni], acc[mi][ni], 0, 0, 0);

    p ^= 1;
  }
#undef STAGE

  // epilogue: C/D layout col=lane&15, row=(lane>>4)*4+reg
  float bv[4];
#pragma unroll
  for (int ni = 0; ni < 4; ni++)
    bv[ni] = bias[(size_t)e * O + n0 + wn + ni * 16 + lr];
#pragma unroll
  for (int mi = 0; mi < 4; mi++) {
#pragma unroll
    for (int rg = 0; rg < 4; rg++) {
      int rl = wm + mi * 16 + q * 4 + rg;
      if (m0 + rl < ce) {
        float s = scS[rl];
        float* orow = out + (size_t)tokS[rl] * O + n0 + wn;
#pragma unroll
        for (int ni = 0; ni < 4; ni++)
          orow[ni * 16 + lr] = (acc[mi][ni][rg] + bv[ni]) * s;
      }
    }
  }
}

extern "C" void kernel_launch(void* const* d_in, const int* in_sizes, int n_in,
                              void* d_out, int out_size, void* d_ws, size_t ws_size,
                              hipStream_t stream)
{
  const float* x    = (const float*)d_in[0];   // [T, D]
  const float* gw   = (const float*)d_in[1];   // [D, 8]
  const float* rule = (const float*)d_in[2];   // [8, 4, 4, 4]
  const float* W    = (const float*)d_in[3];   // [8, 4, D/4, O/4]
  const float* bias = (const float*)d_in[4];   // [8, O]
  float* out = (float*)d_out;

  int D = in_sizes[1] / NEXP;
  int O = in_sizes[4] / NEXP;
  int T = in_sizes[0] / D;
  int Dp = D / 4, Op = O / 4;

  uint8_t* ws = (uint8_t*)d_ws;
  size_t off = 0;
  f16* xb = (f16*)(ws + off);  off += (size_t)T * D * 2;
  f16* wt = (f16*)(ws + off);  off += (size_t)NEXP * O * D * 2;
  int*   gate  = (int*)(ws + off);   off += (size_t)T * 4;
  float* scale = (float*)(ws + off); off += (size_t)T * 4;
  int*   perm  = (int*)(ws + off);   off += (size_t)T * 4;
  off = (off + 255) & ~(size_t)255;
  uint8_t* C = ws + off;
  int*   cnt     = (int*)(C + 0);
  float* probsum = (float*)(C + 32);
  int*   cursor  = (int*)(C + 64);
  int*   ndesc   = (int*)(C + 96);
  int*   offs    = (int*)(C + 128);
  int2*  desc    = (int2*)(C + 192);   // capacity to C+4096

  // zero cnt/probsum/cursor/ndesc (ws is re-poisoned 0xAA before every call)
  hipMemsetAsync(C, 0, 128, stream);

  // fusedA: blocks [0, ngate) gate-role, [ngate, ngate+nwf) wfull-role
  int ngate = T / (4 * TPW);                       // 512
  int nwf = NEXP * (Op / 32) * (Dp / 32);          // 2048
  k_fusedA<<<ngate + nwf, 256, 0, stream>>>(
      x, gw, xb, gate, scale, cnt, probsum, W, rule, wt, D, Dp, Op, O, ngate);

  // fusedB: block 0 plan, blocks 1..T/256 scatter
  k_fusedB<<<1 + T / 256, 256, 0, stream>>>(
      cnt, probsum, gate, offs, ndesc, desc, cursor, perm,
      out + (size_t)T * O, T);

  int maxdesc = T / BM + NEXP;  // worst-case row-block descriptor count
  k_gemm<<<dim3(O / BN, maxdesc), 256, 0, stream>>>(
      xb, wt, bias, perm, cnt, offs, ndesc, desc, scale, out, D, O);
}

// Round 7
// 319.364 us; speedup vs baseline: 1.0185x; 1.0185x over previous
//
#include <hip/hip_runtime.h>
#include <cstdint>
#include <cstddef>

typedef _Float16 f16;
typedef f16 f16x2 __attribute__((ext_vector_type(2)));
typedef f16 f16x4 __attribute__((ext_vector_type(4)));
typedef f16 f16x8 __attribute__((ext_vector_type(8)));
typedef float f32x4 __attribute__((ext_vector_type(4)));

#define NEXP 8
#define BM 128
#define BN 128
#define BK 32
#define NSTAGE 3
#define TPW 4

// async global->LDS, 16B per lane. LDS dest must be wave-uniform base + lane*16
// (staging index is tid*16 so this holds). Global source may be per-lane
// arbitrary (gathered rows / swizzled chunks are fine).
__device__ __forceinline__ void async_cp16(void* lds, const void* gsrc) {
  __builtin_amdgcn_global_load_lds(
      (const __attribute__((address_space(1))) void*)gsrc,
      (__attribute__((address_space(3))) void*)lds, 16, 0, 0);
}

// ---------------- fusedA: gate-role + wfull-role in one dispatch -------------
// Blocks [0, ngate): gating. Blocks [ngate, ...): Wfull^T construction.
// v2: smem union shrunk to 16.9 KB (gate stages gw in 512-d QUARTER passes,
// gws[8][516] = 16.5 KB). The v1 33 KB union capped wfull-role blocks at
// 1/CU (was 3/CU standalone) — occupancy regression that cancelled the
// fusion's launch-gap win.
__global__ __launch_bounds__(256) void k_fusedA(
    const float* __restrict__ x, const float* __restrict__ gw,
    f16* __restrict__ xb, int* __restrict__ gate, float* __restrict__ scale,
    int* __restrict__ cnt, float* __restrict__ probsum,
    const float* __restrict__ Wp, const float* __restrict__ rule,
    f16* __restrict__ wt,
    int D, int Dp, int Op, int O, int ngate)
{
  __shared__ __align__(16) uint8_t smem[16960];
  int tid = threadIdx.x;

  if ((int)blockIdx.x < ngate) {
    // ================= gate role =================
    float (*gws)[516] = (float(*)[516])smem;              // [8][516] = 16.5KB
    float* ps = (float*)(smem + NEXP * 516 * 4);          // [8]
    int*   pc = (int*)(smem + NEXP * 516 * 4 + 32);       // [8]
    int lane = tid & 63, w = tid >> 6;
    if (tid < NEXP) { ps[tid] = 0.f; pc[tid] = 0; }

    int t0 = (blockIdx.x * 4 + w) * TPW;     // wave's first token
    const float* xr = x + (size_t)t0 * D;
    f16* xbr = xb + (size_t)t0 * D;

    float acc[TPW][NEXP] = {};
    int nq = D >> 9;                         // quarter-passes of 512 d each
    for (int qp = 0; qp < nq; qp++) {
      __syncthreads();   // prev pass reads (and ps/pc init) done before restage
      // stage gw[qp*512 + d][e] -> gws[e][d]; coalesced float2 global reads.
      const float2* gsrc = (const float2*)(gw + (size_t)qp * 512 * NEXP);
      for (int i = tid; i < 2048; i += 256) {
        float2 v = gsrc[i];
        int f = i * 2;
        int d = f >> 3, e = f & 7;
        gws[e][d] = v.x;
        gws[e + 1][d] = v.y;
      }
      __syncthreads();

      int dh = qp << 9;
#pragma unroll
      for (int it = 0; it < 2; it++) {
        int d0 = lane * 4 + it * 256;        // local d within this quarter
        float4 xv[TPW];
#pragma unroll
        for (int tp = 0; tp < TPW; tp++) {
          xv[tp] = *(const float4*)(xr + (size_t)tp * D + dh + d0);
          f16x4 h;
          h[0] = (f16)xv[tp].x; h[1] = (f16)xv[tp].y;
          h[2] = (f16)xv[tp].z; h[3] = (f16)xv[tp].w;
          *(f16x4*)(xbr + (size_t)tp * D + dh + d0) = h;
        }
#pragma unroll
        for (int e = 0; e < NEXP; e++) {
          float4 g = *(const float4*)&gws[e][d0];   // conflict-free, reused x4
#pragma unroll
          for (int tp = 0; tp < TPW; tp++)
            acc[tp][e] += xv[tp].x * g.x + xv[tp].y * g.y +
                          xv[tp].z * g.z + xv[tp].w * g.w;
        }
      }
    }

#pragma unroll
    for (int tp = 0; tp < TPW; tp++)
#pragma unroll
      for (int e = 0; e < NEXP; e++) {
        float v = acc[tp][e];
        for (int o = 32; o > 0; o >>= 1) v += __shfl_xor(v, o);
        acc[tp][e] = v;
      }

    if (lane == 0) {
#pragma unroll
      for (int tp = 0; tp < TPW; tp++) {
        float m = acc[tp][0]; int g = 0;
#pragma unroll
        for (int e = 1; e < NEXP; e++)
          if (acc[tp][e] > m) { m = acc[tp][e]; g = e; }
        float pr[NEXP]; float ssum = 0.f;
#pragma unroll
        for (int e = 0; e < NEXP; e++) { pr[e] = __expf(acc[tp][e] - m); ssum += pr[e]; }
        float inv = 1.0f / ssum;
#pragma unroll
        for (int e = 0; e < NEXP; e++) atomicAdd(&ps[e], pr[e] * inv);
        atomicAdd(&pc[g], 1);
        gate[t0 + tp] = g;
        scale[t0 + tp] = pr[g] * inv;
      }
    }
    __syncthreads();
    if (tid < NEXP) {
      atomicAdd(&probsum[tid], ps[tid]);
      atomicAdd(&cnt[tid], pc[tid]);
    }
  } else {
    // ================= wfull role =================
    // wt[e][n][d] = sum_p rule[e,p,a,b] * W[e,p,i,j], d = a*Dp+i, n = b*Op+j.
    float (*Wt)[32][33] = (float(*)[32][33])smem;         // [4][32][33]=16.9KB
    int bid = blockIdx.x - ngate;
    int it = Dp >> 5, jt = Op >> 5;
    int itile = bid % it; bid /= it;
    int jtile = bid % jt; bid /= jt;
    int e = bid;
    int i0 = itile * 32, j0 = jtile * 32;

    for (int idx = tid; idx < 4096; idx += 256) {
      int p = idx >> 10, rem = idx & 1023, ii = rem >> 5, jj = rem & 31;
      Wt[p][ii][jj] = Wp[(size_t)((e * 4 + p) * Dp + i0 + ii) * Op + j0 + jj];
    }
    __syncthreads();

    int r = tid >> 1;        // 0..127 output rows of this block
    int b = r >> 5;          // wave-uniform
    int jj = r & 31;
    int h = tid & 1;         // d-half: i = h*16 + k

    float s[4][4];
#pragma unroll
    for (int p = 0; p < 4; p++)
#pragma unroll
      for (int a = 0; a < 4; a++)
        s[p][a] = rule[((e * 4 + p) * 4 + a) * 4 + b];

    f16x8 outv[4][2];
#pragma unroll
    for (int k = 0; k < 16; k++) {
      int i = h * 16 + k;
      float w0 = Wt[0][i][jj], w1 = Wt[1][i][jj];
      float w2 = Wt[2][i][jj], w3 = Wt[3][i][jj];
#pragma unroll
      for (int a = 0; a < 4; a++) {
        float acc = s[0][a] * w0 + s[1][a] * w1 + s[2][a] * w2 + s[3][a] * w3;
        outv[a][k >> 3][k & 7] = (f16)acc;
      }
    }

    size_t rowbase = ((size_t)e * O + (size_t)b * Op + j0 + jj) * D + i0 + h * 16;
#pragma unroll
    for (int a = 0; a < 4; a++) {
      *(f16x8*)(wt + rowbase + (size_t)a * Dp)     = outv[a][0];
      *(f16x8*)(wt + rowbase + (size_t)a * Dp + 8) = outv[a][1];
    }
  }
}

// ---------------- fusedB: plan (block 0) + scatter (blocks 1..T/256) ---------
__global__ __launch_bounds__(256) void k_fusedB(
    const int* __restrict__ cnt, const float* __restrict__ probsum,
    const int* __restrict__ gate, int* __restrict__ offs,
    int* __restrict__ ndesc, int2* __restrict__ desc,
    int* __restrict__ cursor, int* __restrict__ perm,
    float* __restrict__ otail, int T)
{
  int tid = threadIdx.x;
  if (blockIdx.x == 0) {
    // ---- plan ----
    __shared__ int soffs[NEXP + 1];
    __shared__ int snd;
    __shared__ float sloss;
    __shared__ int2 sdesc[96];
    if (tid == 0) {
      int off = 0, nd = 0; float loss = 0.f;
      for (int e = 0; e < NEXP; e++) {
        soffs[e] = off;
        int c = cnt[e];
        loss += probsum[e] * (float)c;
        for (int m0 = 0; m0 < c; m0 += BM) { sdesc[nd] = make_int2(e, m0); nd++; }
        off += c;
      }
      soffs[NEXP] = off;
      snd = nd;
      sloss = loss;
    }
    __syncthreads();
    if (tid <= NEXP) offs[tid] = soffs[tid];
    if (tid == 9) *ndesc = snd;
    if (tid == 10) {
      float invT = 1.0f / (float)T;
      otail[0] = (float)NEXP * sloss * invT * invT;  // balance loss
    }
    if (tid >= 16 && tid < 16 + NEXP) otail[1 + tid - 16] = (float)cnt[tid - 16];
    for (int i = tid; i < snd; i += 256) desc[i] = sdesc[i];
  } else {
    // ---- scatter ----
    int t = (blockIdx.x - 1) * 256 + tid;
    int g = gate[t];
    int lane = tid & 63;
    // local exclusive scan of cnt (8 ints, L2-broadcast)
    int lofs[NEXP];
    {
      int run = 0;
#pragma unroll
      for (int e = 0; e < NEXP; e++) { lofs[e] = run; run += cnt[e]; }
    }
    int pos = 0;
#pragma unroll
    for (int e = 0; e < NEXP; e++) {
      unsigned long long mask = __ballot(g == e);
      if (mask == 0ull) continue;            // wave-uniform
      int leader = __ffsll((unsigned long long)mask) - 1;
      int base = 0;
      if (lane == leader) base = atomicAdd(&cursor[e], (int)__popcll(mask));
      base = __shfl(base, leader);
      if (g == e) {
        int below = (int)__popcll(mask & ((1ull << lane) - 1ull));
        pos = lofs[e] + base + below;
      }
    }
    perm[pos] = t;
  }
}

// ---------------- K5: gathered top-1 GEMM, v3: ONE barrier per K-step --------
// 128x128 tile, BK=32, NSTAGE=3. v3 deletes the mid-loop lgkmcnt(0)+barrier:
// STAGE is issued AFTER the top barrier with distance 2, into buffer
// (kk+2)%3 — the buffer last ds_read at iteration kk-1. Safety: each wave's
// iter-(kk-1) ds_reads retired before its iter-(kk-1) MFMAs (compiler
// lgkmcnt), which precede iter-kk's top barrier in program order; the stage
// write comes after that barrier -> no read/write race. Tile-readiness is
// unchanged: top-of-loop vmcnt(4) retires this tile's 4 async loads (next
// tile's 4 stay in flight; after STAGE there are 8 outstanding), barrier
// makes it block-wide. Per K-step rendezvous: 2 -> 1.
__global__ __launch_bounds__(256) void k_gemm(
    const f16* __restrict__ xb, const f16* __restrict__ wt,
    const float* __restrict__ bias, const int* __restrict__ perm,
    const int* __restrict__ cnt, const int* __restrict__ offs,
    const int* __restrict__ ndesc, const int2* __restrict__ desc,
    const float* __restrict__ scale, float* __restrict__ out, int D, int O)
{
  if ((int)blockIdx.y >= *ndesc) return;
  int2 dsc = desc[blockIdx.y];
  int e = dsc.x, m0 = dsc.y;
  int ce = cnt[e];
  int seg = offs[e];
  int n0 = blockIdx.x * BN;

  __shared__ f16 Al[NSTAGE][BM * BK];   // 3 x 8KB
  __shared__ f16 Bl[NSTAGE][BN * BK];   // 3 x 8KB
  __shared__ int tokS[BM];
  __shared__ float scS[BM];

  int tid = threadIdx.x;
  if (tid < BM) {
    int idx = m0 + tid; if (idx > ce - 1) idx = ce - 1;  // clamp partial tile
    int tok = perm[seg + idx];
    tokS[tid] = tok;
    scS[tid] = scale[tok];
  }
  __syncthreads();

  // staging: thread owns 16B chunk c of rows r and r+64; fetches global chunk
  // gc = c ^ ((r>>1)&3); MFMA reader un-swizzles with the same xor.
  int r = tid >> 2;   // 0..63
  int c = tid & 3;
  int gc = c ^ ((r >> 1) & 3);
  const f16* a1 = xb + (size_t)tokS[r] * D + gc * 8;
  const f16* a2 = xb + (size_t)tokS[r + 64] * D + gc * 8;
  const f16* b1 = wt + ((size_t)e * O + n0 + r) * D + gc * 8;
  const f16* b2 = wt + ((size_t)e * O + n0 + r + 64) * D + gc * 8;

  int lane = tid & 63;
  int w = tid >> 6;
  int wm = (w & 1) * 64, wn = (w >> 1) * 64;
  int lr = lane & 15, q = lane >> 4;
  int qs = q ^ ((lr >> 1) & 3);  // swizzled read chunk

  f32x4 acc[4][4] = {};
  int nk = D / BK;

#define STAGE(kk, p)                                             \
  do {                                                           \
    async_cp16(&Al[(p)][tid * 8], a1 + (kk) * BK);               \
    async_cp16(&Al[(p)][2048 + tid * 8], a2 + (kk) * BK);        \
    async_cp16(&Bl[(p)][tid * 8], b1 + (kk) * BK);               \
    async_cp16(&Bl[(p)][2048 + tid * 8], b2 + (kk) * BK);        \
  } while (0)

  STAGE(0, 0);
  STAGE(1, 1);

  int p = 0;
  for (int kk = 0; kk < nk; ++kk) {
    // tile kk must be complete; tile kk+1 (4 loads) may stay in flight
    if (kk + 1 < nk)
      asm volatile("s_waitcnt vmcnt(4)\n\ts_barrier" ::: "memory");
    else
      asm volatile("s_waitcnt vmcnt(0)\n\ts_barrier" ::: "memory");

    // stage kk+2 into the buffer last read at iter kk-1 (protected by the
    // barrier above) — no second rendezvous needed.
    if (kk + 2 < nk) {
      int pn = p + 2; if (pn >= NSTAGE) pn -= NSTAGE;
      STAGE(kk + 2, pn);
    }

    f16x8 af[4], bf[4];
#pragma unroll
    for (int mi = 0; mi < 4; mi++)
      af[mi] = *(const f16x8*)&Al[p][(wm + mi * 16 + lr) * BK + qs * 8];
#pragma unroll
    for (int ni = 0; ni < 4; ni++)
      bf[ni] = *(const f16x8*)&Bl[p][(wn + ni * 16 + lr) * BK + qs * 8];

#pragma unroll
    for (int mi = 0; mi < 4; mi++)
#pragma unroll
      for (int ni = 0; ni < 4; ni++)
        acc[mi][ni] = __builtin_amdgcn_mfma_f32_16x16x32_f16(
            af[mi], bf[ni], acc[mi][ni], 0, 0, 0);

    p++; if (p == NSTAGE) p = 0;
  }
#undef STAGE

  // epilogue: C/D layout col=lane&15, row=(lane>>4)*4+reg
  float bv[4];
#pragma unroll
  for (int ni = 0; ni < 4; ni++)
    bv[ni] = bias[(size_t)e * O + n0 + wn + ni * 16 + lr];
#pragma unroll
  for (int mi = 0; mi < 4; mi++) {
#pragma unroll
    for (int rg = 0; rg < 4; rg++) {
      int rl = wm + mi * 16 + q * 4 + rg;
      if (m0 + rl < ce) {
        float s = scS[rl];
        float* orow = out + (size_t)tokS[rl] * O + n0 + wn;
#pragma unroll
        for (int ni = 0; ni < 4; ni++)
          orow[ni * 16 + lr] = (acc[mi][ni][rg] + bv[ni]) * s;
      }
    }
  }
}

extern "C" void kernel_launch(void* const* d_in, const int* in_sizes, int n_in,
                              void* d_out, int out_size, void* d_ws, size_t ws_size,
                              hipStream_t stream)
{
  const float* x    = (const float*)d_in[0];   // [T, D]
  const float* gw   = (const float*)d_in[1];   // [D, 8]
  const float* rule = (const float*)d_in[2];   // [8, 4, 4, 4]
  const float* W    = (const float*)d_in[3];   // [8, 4, D/4, O/4]
  const float* bias = (const float*)d_in[4];   // [8, O]
  float* out = (float*)d_out;

  int D = in_sizes[1] / NEXP;
  int O = in_sizes[4] / NEXP;
  int T = in_sizes[0] / D;
  int Dp = D / 4, Op = O / 4;

  uint8_t* ws = (uint8_t*)d_ws;
  size_t off = 0;
  f16* xb = (f16*)(ws + off);  off += (size_t)T * D * 2;
  f16* wt = (f16*)(ws + off);  off += (size_t)NEXP * O * D * 2;
  int*   gate  = (int*)(ws + off);   off += (size_t)T * 4;
  float* scale = (float*)(ws + off); off += (size_t)T * 4;
  int*   perm  = (int*)(ws + off);   off += (size_t)T * 4;
  off = (off + 255) & ~(size_t)255;
  uint8_t* C = ws + off;
  int*   cnt     = (int*)(C + 0);
  float* probsum = (float*)(C + 32);
  int*   cursor  = (int*)(C + 64);
  int*   ndesc   = (int*)(C + 96);
  int*   offs    = (int*)(C + 128);
  int2*  desc    = (int2*)(C + 192);   // capacity to C+4096

  // zero cnt/probsum/cursor/ndesc (ws is re-poisoned 0xAA before every call)
  hipMemsetAsync(C, 0, 128, stream);

  // fusedA: blocks [0, ngate) gate-role, [ngate, ngate+nwf) wfull-role
  int ngate = T / (4 * TPW);                       // 512
  int nwf = NEXP * (Op / 32) * (Dp / 32);          // 2048
  k_fusedA<<<ngate + nwf, 256, 0, stream>>>(
      x, gw, xb, gate, scale, cnt, probsum, W, rule, wt, D, Dp, Op, O, ngate);

  // fusedB: block 0 plan, blocks 1..T/256 scatter
  k_fusedB<<<1 + T / 256, 256, 0, stream>>>(
      cnt, probsum, gate, offs, ndesc, desc, cursor, perm,
      out + (size_t)T * O, T);

  int maxdesc = T / BM + NEXP;  // worst-case row-block descriptor count
  k_gemm<<<dim3(O / BN, maxdesc), 256, 0, stream>>>(
      xb, wt, bias, perm, cnt, offs, ndesc, desc, scale, out, D, O);
}

// Round 8
// 313.597 us; speedup vs baseline: 1.0373x; 1.0184x over previous
//
#include <hip/hip_runtime.h>
#include <cstdint>
#include <cstddef>

typedef _Float16 f16;
typedef f16 f16x2 __attribute__((ext_vector_type(2)));
typedef f16 f16x4 __attribute__((ext_vector_type(4)));
typedef f16 f16x8 __attribute__((ext_vector_type(8)));
typedef float f32x4 __attribute__((ext_vector_type(4)));

#define NEXP 8
#define BM 128
#define BN 128
#define BK 32
#define NSTAGE 3
#define TPW 4

// async global->LDS, 16B per lane. LDS dest must be wave-uniform base + lane*16
// (staging index is tid*16 so this holds). Global source may be per-lane
// arbitrary (gathered rows / swizzled chunks are fine).
__device__ __forceinline__ void async_cp16(void* lds, const void* gsrc) {
  __builtin_amdgcn_global_load_lds(
      (const __attribute__((address_space(1))) void*)gsrc,
      (__attribute__((address_space(3))) void*)lds, 16, 0, 0);
}

// ---------------- fusedA: gate-role + wfull-role in one dispatch -------------
// Blocks [0, ngate): gating. Blocks [ngate, ...): Wfull^T construction.
// smem union 16.9 KB (gate stages gw in 512-d quarter-passes, gws[8][516];
// wfull uses Wt[4][32][33]) -> both roles keep 3 blocks/CU residency.
__global__ __launch_bounds__(256) void k_fusedA(
    const float* __restrict__ x, const float* __restrict__ gw,
    f16* __restrict__ xb, int* __restrict__ gate, float* __restrict__ scale,
    int* __restrict__ cnt, float* __restrict__ probsum,
    const float* __restrict__ Wp, const float* __restrict__ rule,
    f16* __restrict__ wt,
    int D, int Dp, int Op, int O, int ngate)
{
  __shared__ __align__(16) uint8_t smem[16960];
  int tid = threadIdx.x;

  if ((int)blockIdx.x < ngate) {
    // ================= gate role =================
    float (*gws)[516] = (float(*)[516])smem;              // [8][516] = 16.5KB
    float* ps = (float*)(smem + NEXP * 516 * 4);          // [8]
    int*   pc = (int*)(smem + NEXP * 516 * 4 + 32);       // [8]
    int lane = tid & 63, w = tid >> 6;
    if (tid < NEXP) { ps[tid] = 0.f; pc[tid] = 0; }

    int t0 = (blockIdx.x * 4 + w) * TPW;     // wave's first token
    const float* xr = x + (size_t)t0 * D;
    f16* xbr = xb + (size_t)t0 * D;

    float acc[TPW][NEXP] = {};
    int nq = D >> 9;                         // quarter-passes of 512 d each
    for (int qp = 0; qp < nq; qp++) {
      __syncthreads();   // prev pass reads (and ps/pc init) done before restage
      // stage gw[qp*512 + d][e] -> gws[e][d]; coalesced float2 global reads.
      const float2* gsrc = (const float2*)(gw + (size_t)qp * 512 * NEXP);
      for (int i = tid; i < 2048; i += 256) {
        float2 v = gsrc[i];
        int f = i * 2;
        int d = f >> 3, e = f & 7;
        gws[e][d] = v.x;
        gws[e + 1][d] = v.y;
      }
      __syncthreads();

      int dh = qp << 9;
#pragma unroll
      for (int it = 0; it < 2; it++) {
        int d0 = lane * 4 + it * 256;        // local d within this quarter
        float4 xv[TPW];
#pragma unroll
        for (int tp = 0; tp < TPW; tp++) {
          xv[tp] = *(const float4*)(xr + (size_t)tp * D + dh + d0);
          f16x4 h;
          h[0] = (f16)xv[tp].x; h[1] = (f16)xv[tp].y;
          h[2] = (f16)xv[tp].z; h[3] = (f16)xv[tp].w;
          *(f16x4*)(xbr + (size_t)tp * D + dh + d0) = h;
        }
#pragma unroll
        for (int e = 0; e < NEXP; e++) {
          float4 g = *(const float4*)&gws[e][d0];   // conflict-free, reused x4
#pragma unroll
          for (int tp = 0; tp < TPW; tp++)
            acc[tp][e] += xv[tp].x * g.x + xv[tp].y * g.y +
                          xv[tp].z * g.z + xv[tp].w * g.w;
        }
      }
    }

#pragma unroll
    for (int tp = 0; tp < TPW; tp++)
#pragma unroll
      for (int e = 0; e < NEXP; e++) {
        float v = acc[tp][e];
        for (int o = 32; o > 0; o >>= 1) v += __shfl_xor(v, o);
        acc[tp][e] = v;
      }

    if (lane == 0) {
#pragma unroll
      for (int tp = 0; tp < TPW; tp++) {
        float m = acc[tp][0]; int g = 0;
#pragma unroll
        for (int e = 1; e < NEXP; e++)
          if (acc[tp][e] > m) { m = acc[tp][e]; g = e; }
        float pr[NEXP]; float ssum = 0.f;
#pragma unroll
        for (int e = 0; e < NEXP; e++) { pr[e] = __expf(acc[tp][e] - m); ssum += pr[e]; }
        float inv = 1.0f / ssum;
#pragma unroll
        for (int e = 0; e < NEXP; e++) atomicAdd(&ps[e], pr[e] * inv);
        atomicAdd(&pc[g], 1);
        gate[t0 + tp] = g;
        scale[t0 + tp] = pr[g] * inv;
      }
    }
    __syncthreads();
    if (tid < NEXP) {
      atomicAdd(&probsum[tid], ps[tid]);
      atomicAdd(&cnt[tid], pc[tid]);
    }
  } else {
    // ================= wfull role =================
    // wt[e][n][d] = sum_p rule[e,p,a,b] * W[e,p,i,j], d = a*Dp+i, n = b*Op+j.
    float (*Wt)[32][33] = (float(*)[32][33])smem;         // [4][32][33]=16.9KB
    int bid = blockIdx.x - ngate;
    int it = Dp >> 5, jt = Op >> 5;
    int itile = bid % it; bid /= it;
    int jtile = bid % jt; bid /= jt;
    int e = bid;
    int i0 = itile * 32, j0 = jtile * 32;

    for (int idx = tid; idx < 4096; idx += 256) {
      int p = idx >> 10, rem = idx & 1023, ii = rem >> 5, jj = rem & 31;
      Wt[p][ii][jj] = Wp[(size_t)((e * 4 + p) * Dp + i0 + ii) * Op + j0 + jj];
    }
    __syncthreads();

    int r = tid >> 1;        // 0..127 output rows of this block
    int b = r >> 5;          // wave-uniform
    int jj = r & 31;
    int h = tid & 1;         // d-half: i = h*16 + k

    float s[4][4];
#pragma unroll
    for (int p = 0; p < 4; p++)
#pragma unroll
      for (int a = 0; a < 4; a++)
        s[p][a] = rule[((e * 4 + p) * 4 + a) * 4 + b];

    f16x8 outv[4][2];
#pragma unroll
    for (int k = 0; k < 16; k++) {
      int i = h * 16 + k;
      float w0 = Wt[0][i][jj], w1 = Wt[1][i][jj];
      float w2 = Wt[2][i][jj], w3 = Wt[3][i][jj];
#pragma unroll
      for (int a = 0; a < 4; a++) {
        float acc = s[0][a] * w0 + s[1][a] * w1 + s[2][a] * w2 + s[3][a] * w3;
        outv[a][k >> 3][k & 7] = (f16)acc;
      }
    }

    size_t rowbase = ((size_t)e * O + (size_t)b * Op + j0 + jj) * D + i0 + h * 16;
#pragma unroll
    for (int a = 0; a < 4; a++) {
      *(f16x8*)(wt + rowbase + (size_t)a * Dp)     = outv[a][0];
      *(f16x8*)(wt + rowbase + (size_t)a * Dp + 8) = outv[a][1];
    }
  }
}

// ---------------- fusedB: plan (block 0) + scatter (blocks 1..T/256) ---------
__global__ __launch_bounds__(256) void k_fusedB(
    const int* __restrict__ cnt, const float* __restrict__ probsum,
    const int* __restrict__ gate, int* __restrict__ offs,
    int* __restrict__ ndesc, int2* __restrict__ desc,
    int* __restrict__ cursor, int* __restrict__ perm,
    float* __restrict__ otail, int T)
{
  int tid = threadIdx.x;
  if (blockIdx.x == 0) {
    // ---- plan ----
    __shared__ int soffs[NEXP + 1];
    __shared__ int snd;
    __shared__ float sloss;
    __shared__ int2 sdesc[96];
    if (tid == 0) {
      int off = 0, nd = 0; float loss = 0.f;
      for (int e = 0; e < NEXP; e++) {
        soffs[e] = off;
        int c = cnt[e];
        loss += probsum[e] * (float)c;
        for (int m0 = 0; m0 < c; m0 += BM) { sdesc[nd] = make_int2(e, m0); nd++; }
        off += c;
      }
      soffs[NEXP] = off;
      snd = nd;
      sloss = loss;
    }
    __syncthreads();
    if (tid <= NEXP) offs[tid] = soffs[tid];
    if (tid == 9) *ndesc = snd;
    if (tid == 10) {
      float invT = 1.0f / (float)T;
      otail[0] = (float)NEXP * sloss * invT * invT;  // balance loss
    }
    if (tid >= 16 && tid < 16 + NEXP) otail[1 + tid - 16] = (float)cnt[tid - 16];
    for (int i = tid; i < snd; i += 256) desc[i] = sdesc[i];
  } else {
    // ---- scatter ----
    int t = (blockIdx.x - 1) * 256 + tid;
    int g = gate[t];
    int lane = tid & 63;
    // local exclusive scan of cnt (8 ints, L2-broadcast)
    int lofs[NEXP];
    {
      int run = 0;
#pragma unroll
      for (int e = 0; e < NEXP; e++) { lofs[e] = run; run += cnt[e]; }
    }
    int pos = 0;
#pragma unroll
    for (int e = 0; e < NEXP; e++) {
      unsigned long long mask = __ballot(g == e);
      if (mask == 0ull) continue;            // wave-uniform
      int leader = __ffsll((unsigned long long)mask) - 1;
      int base = 0;
      if (lane == leader) base = atomicAdd(&cursor[e], (int)__popcll(mask));
      base = __shfl(base, leader);
      if (g == e) {
        int below = (int)__popcll(mask & ((1ull << lane) - 1ull));
        pos = lofs[e] + base + below;
      }
    }
    perm[pos] = t;
  }
}

// ---------------- K5: gathered top-1 GEMM ----------------
// 128x128 tile, BK=32, 3-stage LDS pipeline (prefetch distance 2), fine
// vmcnt barriers, XOR bank swizzle. Grid ncol-fastest for A/B cache reuse.
// FROZEN — round-0 kernel verbatim (121-122 us, best measured). Variants
// tried and rejected: 256x256 8-phase x2 (128/138 us), NSTAGE=2 (123.5),
// single-barrier distance-2 staging (133). The two-barrier schedule wins
// because ds_reads issue BEFORE the lgkmcnt(0)+barrier, so fragments are
// in-register when waves clear it and MFMAs issue immediately.
__global__ __launch_bounds__(256) void k_gemm(
    const f16* __restrict__ xb, const f16* __restrict__ wt,
    const float* __restrict__ bias, const int* __restrict__ perm,
    const int* __restrict__ cnt, const int* __restrict__ offs,
    const int* __restrict__ ndesc, const int2* __restrict__ desc,
    const float* __restrict__ scale, float* __restrict__ out, int D, int O)
{
  if ((int)blockIdx.y >= *ndesc) return;
  int2 dsc = desc[blockIdx.y];
  int e = dsc.x, m0 = dsc.y;
  int ce = cnt[e];
  int seg = offs[e];
  int n0 = blockIdx.x * BN;

  __shared__ f16 Al[NSTAGE][BM * BK];   // 3 x 8KB
  __shared__ f16 Bl[NSTAGE][BN * BK];   // 3 x 8KB
  __shared__ int tokS[BM];
  __shared__ float scS[BM];

  int tid = threadIdx.x;
  if (tid < BM) {
    int idx = m0 + tid; if (idx > ce - 1) idx = ce - 1;  // clamp partial tile
    int tok = perm[seg + idx];
    tokS[tid] = tok;
    scS[tid] = scale[tok];
  }
  __syncthreads();

  // staging: thread owns 16B chunk c of rows r and r+64; fetches global chunk
  // gc = c ^ ((r>>1)&3); MFMA reader un-swizzles with the same xor.
  int r = tid >> 2;   // 0..63
  int c = tid & 3;
  int gc = c ^ ((r >> 1) & 3);
  const f16* a1 = xb + (size_t)tokS[r] * D + gc * 8;
  const f16* a2 = xb + (size_t)tokS[r + 64] * D + gc * 8;
  const f16* b1 = wt + ((size_t)e * O + n0 + r) * D + gc * 8;
  const f16* b2 = wt + ((size_t)e * O + n0 + r + 64) * D + gc * 8;

  int lane = tid & 63;
  int w = tid >> 6;
  int wm = (w & 1) * 64, wn = (w >> 1) * 64;
  int lr = lane & 15, q = lane >> 4;
  int qs = q ^ ((lr >> 1) & 3);  // swizzled read chunk

  f32x4 acc[4][4] = {};
  int nk = D / BK;

#define STAGE(kk, p)                                             \
  do {                                                           \
    async_cp16(&Al[(p)][tid * 8], a1 + (kk) * BK);               \
    async_cp16(&Al[(p)][2048 + tid * 8], a2 + (kk) * BK);        \
    async_cp16(&Bl[(p)][tid * 8], b1 + (kk) * BK);               \
    async_cp16(&Bl[(p)][2048 + tid * 8], b2 + (kk) * BK);        \
  } while (0)

  STAGE(0, 0);
  STAGE(1, 1);
  STAGE(2, 2);

  int p = 0;
  for (int kk = 0; kk < nk; ++kk) {
    // tile kk must be complete; tiles kk+1, kk+2 (8 loads) may stay in flight
    int rem = nk - 1 - kk;
    if (rem >= 2)
      asm volatile("s_waitcnt vmcnt(8)\n\ts_barrier" ::: "memory");
    else if (rem == 1)
      asm volatile("s_waitcnt vmcnt(4)\n\ts_barrier" ::: "memory");
    else
      asm volatile("s_waitcnt vmcnt(0)\n\ts_barrier" ::: "memory");

    f16x8 af[4], bf[4];
#pragma unroll
    for (int mi = 0; mi < 4; mi++)
      af[mi] = *(const f16x8*)&Al[p][(wm + mi * 16 + lr) * BK + qs * 8];
#pragma unroll
    for (int ni = 0; ni < 4; ni++)
      bf[ni] = *(const f16x8*)&Bl[p][(wn + ni * 16 + lr) * BK + qs * 8];

    // all waves' ds_reads of buffer p done -> safe to restage it
    asm volatile("s_waitcnt lgkmcnt(0)\n\ts_barrier" ::: "memory");
    if (kk + NSTAGE < nk) STAGE(kk + NSTAGE, p);

#pragma unroll
    for (int mi = 0; mi < 4; mi++)
#pragma unroll
      for (int ni = 0; ni < 4; ni++)
        acc[mi][ni] = __builtin_amdgcn_mfma_f32_16x16x32_f16(
            af[mi], bf[ni], acc[mi][ni], 0, 0, 0);

    p++; if (p == NSTAGE) p = 0;
  }
#undef STAGE

  // epilogue: C/D layout col=lane&15, row=(lane>>4)*4+reg
  float bv[4];
#pragma unroll
  for (int ni = 0; ni < 4; ni++)
    bv[ni] = bias[(size_t)e * O + n0 + wn + ni * 16 + lr];
#pragma unroll
  for (int mi = 0; mi < 4; mi++) {
#pragma unroll
    for (int rg = 0; rg < 4; rg++) {
      int rl = wm + mi * 16 + q * 4 + rg;
      if (m0 + rl < ce) {
        float s = scS[rl];
        float* orow = out + (size_t)tokS[rl] * O + n0 + wn;
#pragma unroll
        for (int ni = 0; ni < 4; ni++)
          orow[ni * 16 + lr] = (acc[mi][ni][rg] + bv[ni]) * s;
      }
    }
  }
}

extern "C" void kernel_launch(void* const* d_in, const int* in_sizes, int n_in,
                              void* d_out, int out_size, void* d_ws, size_t ws_size,
                              hipStream_t stream)
{
  const float* x    = (const float*)d_in[0];   // [T, D]
  const float* gw   = (const float*)d_in[1];   // [D, 8]
  const float* rule = (const float*)d_in[2];   // [8, 4, 4, 4]
  const float* W    = (const float*)d_in[3];   // [8, 4, D/4, O/4]
  const float* bias = (const float*)d_in[4];   // [8, O]
  float* out = (float*)d_out;

  int D = in_sizes[1] / NEXP;
  int O = in_sizes[4] / NEXP;
  int T = in_sizes[0] / D;
  int Dp = D / 4, Op = O / 4;

  uint8_t* ws = (uint8_t*)d_ws;
  size_t off = 0;
  f16* xb = (f16*)(ws + off);  off += (size_t)T * D * 2;
  f16* wt = (f16*)(ws + off);  off += (size_t)NEXP * O * D * 2;
  int*   gate  = (int*)(ws + off);   off += (size_t)T * 4;
  float* scale = (float*)(ws + off); off += (size_t)T * 4;
  int*   perm  = (int*)(ws + off);   off += (size_t)T * 4;
  off = (off + 255) & ~(size_t)255;
  uint8_t* C = ws + off;
  int*   cnt     = (int*)(C + 0);
  float* probsum = (float*)(C + 32);
  int*   cursor  = (int*)(C + 64);
  int*   ndesc   = (int*)(C + 96);
  int*   offs    = (int*)(C + 128);
  int2*  desc    = (int2*)(C + 192);   // capacity to C+4096

  // zero cnt/probsum/cursor/ndesc (ws is re-poisoned 0xAA before every call)
  hipMemsetAsync(C, 0, 128, stream);

  // fusedA: blocks [0, ngate) gate-role, [ngate, ngate+nwf) wfull-role
  int ngate = T / (4 * TPW);                       // 512
  int nwf = NEXP * (Op / 32) * (Dp / 32);          // 2048
  k_fusedA<<<ngate + nwf, 256, 0, stream>>>(
      x, gw, xb, gate, scale, cnt, probsum, W, rule, wt, D, Dp, Op, O, ngate);

  // fusedB: block 0 plan, blocks 1..T/256 scatter
  k_fusedB<<<1 + T / 256, 256, 0, stream>>>(
      cnt, probsum, gate, offs, ndesc, desc, cursor, perm,
      out + (size_t)T * O, T);

  int maxdesc = T / BM + NEXP;  // worst-case row-block descriptor count
  k_gemm<<<dim3(O / BN, maxdesc), 256, 0, stream>>>(
      xb, wt, bias, perm, cnt, offs, ndesc, desc, scale, out, D, O);
}